// Round 7
// baseline (34.753 us; speedup 1.0000x reference)
//
#include <hip/hip_runtime.h>
#include <math.h>

// Problem geometry (fixed by the reference setup)
#define CH       48
#define DIM      64
#define SPATIAL  (DIM * DIM * DIM)   // 262144 per (b, c)
#define NB       2
#define VOL      (NB * SPATIAL)      // 524288 per scale volume
#define NS       3
#define CSLAB    (SPATIAL / 4)       // 65536 f4 per (b,c) slab
#define CK_F4    512                 // f4 per kA block chunk (32 W-rows, 8 KB)

#define ZT_PLANE 4096                // (d,h) plane in f4 units, per (s,b,w4)
#define DT       4                   // d-tile in kernel B
#define DTH      (DT + 6)            // with +-3 halo
#define NITEM    (NS * DTH * DIM)    // 1920 tile entries

typedef float f4 __attribute__((ext_vector_type(4)));

// -------------------------------------------------------------------------
// A: channel reduction + W box-sum -> zT[s][b][w4][d][h] (transposed).
// KEY CHANGE vs R6: each block reads 8 KB CONTIGUOUS per channel (2 rounds
// of perfectly-coalesced 4 KB wave loads) before the +1 MB channel jump,
// instead of 1 KB runs.  Tests the DRAM run-length theory for the stuck
// ~4 TB/s x-read.  256 blocks x 256 threads; acc[3][2] f4 in VGPRs;
// LDS transpose (17-pad, conflict-free) then W-pool + transposed store.
// -------------------------------------------------------------------------
__global__ __launch_bounds__(256) void kA(
        const float* __restrict__ x,
        const float* __restrict__ fw,
        float* __restrict__ zt) {
    __shared__ float sw[NS * CH];
    __shared__ f4 tile[NS][32][17];          // +1 pad: no bank conflicts
    const int tid = threadIdx.x;
    if (tid < NS * CH) sw[tid] = fw[tid];
    __syncthreads();

    const int b  = blockIdx.x >> 7;          // 0..1
    const int ck = blockIdx.x & 127;         // chunk within b (512 f4 each)
    const f4* xb = (const f4*)x + (size_t)b * CH * CSLAB + ck * CK_F4 + tid;

    f4 a00 = {0,0,0,0}, a01 = {0,0,0,0};
    f4 a10 = {0,0,0,0}, a11 = {0,0,0,0};
    f4 a20 = {0,0,0,0}, a21 = {0,0,0,0};
    #pragma unroll 8
    for (int c = 0; c < CH; ++c) {
        f4 v0 = __builtin_nontemporal_load(&xb[(size_t)c * CSLAB]);
        f4 v1 = __builtin_nontemporal_load(&xb[(size_t)c * CSLAB + 256]);
        float w0 = sw[c], w1 = sw[CH + c], w2 = sw[2 * CH + c];
        a00 += w0 * v0; a01 += w0 * v1;
        a10 += w1 * v0; a11 += w1 * v1;
        a20 += w2 * v0; a21 += w2 * v1;
    }

    // LDS transpose: chunk-f4 index = tid (j=0) and tid+256 (j=1)
    //   row = idx>>4 (W-row within chunk, 0..31), col = idx&15 (f4 along W)
    const int tr = tid >> 4, tc = tid & 15;
    tile[0][tr][tc] = a00; tile[0][tr + 16][tc] = a01;
    tile[1][tr][tc] = a10; tile[1][tr + 16][tc] = a11;
    tile[2][tr][tc] = a20; tile[2][tr + 16][tc] = a21;
    __syncthreads();

    // W box-sum: thread -> (row r, f4-pair k0,k0+1); zero past row ends
    // == reference zero padding (count_include_pad).
    const int r  = tid >> 3;                 // 0..31
    const int k0 = (tid & 7) * 2;            // 0,2,...,14
    const int dh = ck * 32 + r;              // d*64 + h
    const f4 zero = {0,0,0,0};
    f4* zt4 = (f4*)zt;
    #pragma unroll
    for (int s = 0; s < NS; ++s) {
        f4 A = (k0 > 0)  ? tile[s][r][k0 - 1] : zero;
        f4 B = tile[s][r][k0];
        f4 C = tile[s][r][k0 + 1];
        f4 D = (k0 < 14) ? tile[s][r][k0 + 2] : zero;
        float fa[16] = {A.x, A.y, A.z, A.w, B.x, B.y, B.z, B.w,
                        C.x, C.y, C.z, C.w, D.x, D.y, D.z, D.w};
        const int p = s + 1;
        f4 r0, r1;
        #pragma unroll
        for (int j = 0; j < 4; ++j) {
            float s0 = 0.f, s1 = 0.f;
            #pragma unroll
            for (int i = -3; i <= 3; ++i) {
                if (i >= -p && i <= p) {
                    s0 += fa[4 + j + i];
                    s1 += fa[8 + j + i];
                }
            }
            r0[j] = s0; r1[j] = s1;
        }
        // transposed store: zT[s][b][w4][d][h]
        zt4[((size_t)(s * NB + b) * 16 + k0)     * ZT_PLANE + dh] = r0;
        zt4[((size_t)(s * NB + b) * 16 + k0 + 1) * ZT_PLANE + dh] = r1;
    }
}

// -------------------------------------------------------------------------
// B: fused H box-sum + D box-sum + 1/k^3 + cross-scale sum + bias + sigmoid.
// 512 blocks: block = (b, w4, d-tile of 4). Loads zT tile (30 KB) fully
// contiguous, H-pools in place (regs across a barrier), D-pools from LDS,
// writes final output.  (unchanged from R6)
// -------------------------------------------------------------------------
__global__ __launch_bounds__(256) void kB(
        const float* __restrict__ zt,
        const float* __restrict__ fb,
        float* __restrict__ out) {
    __shared__ f4 tile[NS][DTH][DIM];        // 1920 f4 = 30 KB
    const int tid = threadIdx.x;
    const int bid = blockIdx.x;              // 2*16*16 = 512 blocks
    const int w4  = bid & 15;
    const int d0  = ((bid >> 4) & 15) * DT;
    const int b   = bid >> 8;

    const f4* zt4 = (const f4*)zt;
    #pragma unroll
    for (int s = 0; s < NS; ++s) {
        const f4* src = zt4 + ((size_t)(s * NB + b) * 16 + w4) * ZT_PLANE;
        #pragma unroll
        for (int t = 0; t < (DTH * DIM + 255) / 256; ++t) {
            int i = tid + t * 256;
            if (i < DTH * DIM) {
                int dd = i >> 6, h = i & 63;
                int gd = d0 - 3 + dd;
                f4 v = {0,0,0,0};
                if (gd >= 0 && gd < DIM) v = src[gd * 64 + h];
                tile[s][dd][h] = v;          // zero-filled halo == zero padding
            }
        }
    }
    __syncthreads();

    // H-pool in place: compute all windows into regs, barrier, write back.
    f4 acc[(NITEM + 255) / 256];             // fixed-trip -> stays in VGPRs
    #pragma unroll
    for (int t = 0; t < (NITEM + 255) / 256; ++t) {
        int j = tid + t * 256;
        f4 a = {0,0,0,0};
        if (j < NITEM) {
            int s   = j / (DTH * DIM);
            int rem = j - s * (DTH * DIM);
            int dd  = rem >> 6, h = rem & 63;
            int p   = s + 1;
            int lo  = h - p; if (lo < 0)  lo = 0;
            int hi  = h + p; if (hi > 63) hi = 63;
            for (int hh = lo; hh <= hi; ++hh) a += tile[s][dd][hh];
        }
        acc[t] = a;
    }
    __syncthreads();
    #pragma unroll
    for (int t = 0; t < (NITEM + 255) / 256; ++t) {
        int j = tid + t * 256;
        if (j < NITEM) {
            int s   = j / (DTH * DIM);
            int rem = j - s * (DTH * DIM);
            tile[s][rem >> 6][rem & 63] = acc[t];
        }
    }
    __syncthreads();

    // D-pool + combine scales + bias + sigmoid -> final output (256 f4).
    const float inv[NS] = {1.f / 27.f, 1.f / 125.f, 1.f / 343.f};
    const float bias = fb[0];
    const int ddp = tid >> 6, h = tid & 63;
    const int d   = d0 + ddp;
    f4 a2 = {bias, bias, bias, bias};
    #pragma unroll
    for (int s = 0; s < NS; ++s) {
        int p = s + 1;
        f4 a = {0,0,0,0};
        #pragma unroll
        for (int i = -3; i <= 3; ++i)        // halo rows already zero
            if (i >= -p && i <= p) a += tile[s][ddp + 3 + i][h];
        a2 += a * inv[s];
    }
    f4 r;
    #pragma unroll
    for (int jj = 0; jj < 4; ++jj) r[jj] = 1.f / (1.f + __expf(-a2[jj]));
    __builtin_nontemporal_store(r,
        &((f4*)out)[(size_t)b * (SPATIAL / 4) + (size_t)d * 1024 + h * 16 + w4]);
}

// -------------------------------------------------------------------------
extern "C" void kernel_launch(void* const* d_in, const int* in_sizes, int n_in,
                              void* d_out, int out_size, void* d_ws, size_t ws_size,
                              hipStream_t stream) {
    const float* x  = (const float*)d_in[0];   // (2, 48, 64, 64, 64) f32
    const float* fw = (const float*)d_in[1];   // (1, 144) f32
    const float* fb = (const float*)d_in[2];   // (1,) f32
    float* out = (float*)d_out;                // (2, 1, 64, 64, 64) f32

    float* zt = (float*)d_ws;                  // 3*VOL floats = 6.29 MB

    // A: channel mix + W box-sum -> zT (transposed), 256 blocks
    kA<<<NB * 128, 256, 0, stream>>>(x, fw, zt);
    // B: H-pool + D-pool + scale + bias + sigmoid -> out, 512 blocks
    kB<<<NB * 16 * (DIM / DT), 256, 0, stream>>>(zt, fb, out);
}